// Round 3
// baseline (259.036 us; speedup 1.0000x reference)
//
#include <hip/hip_runtime.h>

#define H    112
#define W    112
#define HW   12544
#define CIN  64
#define COUT 128
#define BATCH 8
#define KK   9
#define OFFC 18
#define EPS  1e-5f
#define TP   32      // pixels per deform block
#define KDIM 576     // CIN*KK
#define KHALF 288    // K split in two passes
#define KPAD2 296    // samp row stride (elements): 148 dwords -> good bank spread
#define NB   3136    // deform grid size (HW/TP * BATCH)
#define YST  40      // y staging row stride (ushorts): 20 dwords -> spread
#define SSTRIDE 16   // stats padding: one float per 64B line

typedef unsigned short ushort;
typedef unsigned int uint;
typedef __attribute__((ext_vector_type(8))) short short8;
typedef __attribute__((ext_vector_type(4))) float floatx4;
typedef __attribute__((ext_vector_type(2))) float f32x2;

__device__ __forceinline__ ushort f2bf(float f) {
  uint u = __float_as_uint(f);
  u = (u + 0x7FFFu + ((u >> 16) & 1u)) >> 16;   // RNE
  return (ushort)u;
}

// pack two fp32 -> two bf16 (RNE-ish) in one v_perm
__device__ __forceinline__ uint pack_bf2(float f0, float f1) {
  uint u0 = __float_as_uint(f0) + 0x8000u;
  uint u1 = __float_as_uint(f1) + 0x8000u;
  return __builtin_amdgcn_perm(u1, u0, 0x07060302u);
}

// unpack a dword of 2 bf16 -> f32x2
__device__ __forceinline__ f32x2 up2(uint u) {
  f32x2 r;
  r.x = __uint_as_float(u << 16);
  r.y = __uint_as_float(u & 0xFFFF0000u);
  return r;
}

// ---------------- K0: transpose x -> xTb bf16 [B][HW][CIN] + weight prep + stats zero ----------------
__global__ __launch_bounds__(256) void k_prep(
    const float* __restrict__ x, const float* __restrict__ w_off,
    const float* __restrict__ w_dcn, ushort* __restrict__ xTb,
    ushort* __restrict__ w_offT, ushort* __restrict__ w_mf,
    float* __restrict__ stats) {
  if (blockIdx.y < BATCH) {
    __shared__ float tile[64][65];
    int b = blockIdx.y;
    int p0 = blockIdx.x * 64;
    int tid = threadIdx.x;
    int j = tid & 63, cb = tid >> 6;
#pragma unroll
    for (int i = 0; i < 16; ++i) {
      int ci = cb * 16 + i;
      tile[ci][j] = x[((size_t)(b * CIN + ci)) * HW + p0 + j];
    }
    __syncthreads();
    int px = tid >> 2, ciq = tid & 3;
#pragma unroll
    for (int g = 0; g < 4; ++g) {
      int ci = ciq * 16 + g * 4;
      uint lo = pack_bf2(tile[ci + 0][px], tile[ci + 1][px]);
      uint hi = pack_bf2(tile[ci + 2][px], tile[ci + 3][px]);
      *(uint2*)&xTb[((size_t)b * HW + p0 + px) * 64 + ci] = make_uint2(lo, hi);
    }
  } else {
    int tid = threadIdx.x;
    if (blockIdx.x == 0) {   // zero padded stats (stream-ordered before k_deform atomics)
#pragma unroll
      for (int i = tid; i < 256 * SSTRIDE; i += 256) stats[i] = 0.f;
    }
    // weight prep: w_offT[oc<32][kk*64+ci], w_mf[co][h*288 + kk*32 + cil]
    const int TOT = 32 * KDIM + COUT * KDIM;
    for (int i = blockIdx.x * 256 + tid; i < TOT; i += 196 * 256) {
      if (i < 32 * KDIM) {
        int oc = i / KDIM, k = i - oc * KDIM;
        int kk = k >> 6, ci = k & 63;
        float v = (oc < OFFC) ? w_off[(oc * CIN + ci) * KK + kk] : 0.f;
        w_offT[i] = f2bf(v);
      } else {
        int jj = i - 32 * KDIM;
        int co = jj / KDIM, k = jj - co * KDIM;
        int h2 = k / KHALF, r = k - h2 * KHALF;
        int kk = r >> 5, cil = r & 31;
        int ci = h2 * 32 + cil;
        w_mf[jj] = f2bf(w_dcn[(co * CIN + ci) * KK + kk]);
      }
    }
  }
}

// ---------------- K1: offset conv as register-resident bf16 MFMA (standalone: latency hides) ----------------
__global__ __launch_bounds__(256) void k_offset_conv(
    const ushort* __restrict__ xTb, const ushort* __restrict__ w_offT,
    const float* __restrict__ bias, float* __restrict__ out) {
  int b = blockIdx.y;
  int wave = threadIdx.x >> 6, lane = threadIdx.x & 63;
  int row16 = lane & 15, quad = lane >> 4;
  int p = blockIdx.x * 64 + wave * 16 + row16;
  int ho = p / W, wo = p - ho * W;
  const ushort* xb = xTb + (size_t)b * HW * 64;

  short8 Bf[18];
#pragma unroll
  for (int ks = 0; ks < 18; ++ks) {
    int kk = ks >> 1;
    int ci0 = (ks & 1) * 32 + quad * 8;
    int kh = kk / 3, kw = kk - kh * 3;
    int yy = ho + kh - 1, xx = wo + kw - 1;
    bool valid = (yy >= 0) & (yy < H) & (xx >= 0) & (xx < W);
    short8 v = {0, 0, 0, 0, 0, 0, 0, 0};
    if (valid) v = *(const short8*)(xb + ((size_t)(yy * W + xx) << 6) + ci0);
    Bf[ks] = v;
  }
  floatx4 acc0 = {0.f, 0.f, 0.f, 0.f}, acc1 = acc0;
  const ushort* wa0 = w_offT + row16 * KDIM + quad * 8;
  const ushort* wa1 = w_offT + (16 + row16) * KDIM + quad * 8;
#pragma unroll
  for (int ks = 0; ks < 18; ++ks) {
    short8 A0 = *(const short8*)(wa0 + ks * 32);
    short8 A1 = *(const short8*)(wa1 + ks * 32);
    acc0 = __builtin_amdgcn_mfma_f32_16x16x32_bf16(A0, Bf[ks], acc0, 0, 0, 0);
    acc1 = __builtin_amdgcn_mfma_f32_16x16x32_bf16(A1, Bf[ks], acc1, 0, 0, 0);
  }
  float* ob = out + (size_t)b * OFFC * HW;
#pragma unroll
  for (int reg = 0; reg < 4; ++reg) {
    int oc = quad * 4 + reg;
    ob[(size_t)oc * HW + p] = acc0[reg] + bias[oc];
    int oc1 = 16 + oc;
    if (oc1 < OFFC) ob[(size_t)oc1 * HW + p] = acc1[reg] + bias[oc1];
  }
}

// ---------------- K2: deform conv (K-split bf16 MFMA) -> y bf16 + atomic BN stats ----------------
__global__ __launch_bounds__(256, 6) void k_deform(
    const ushort* __restrict__ xTb, const float* __restrict__ off,
    const ushort* __restrict__ w_mf, ushort* __restrict__ y,
    float* __restrict__ stats) {
  __shared__ float4  s_w[KK][TP];                          // 4608 B
  __shared__ ushort4 s_ip[KK][TP];                         // 2304 B (pixel indices, <<6 at use)
  __shared__ __align__(16) char smem_raw[TP * KPAD2 * 2];  // 18944 B: samp -> yst
  ushort (*samp)[KPAD2] = (ushort(*)[KPAD2])smem_raw;

  int b = blockIdx.y;
  int p0 = blockIdx.x * TP;
  int tid = threadIdx.x;
  const ushort* xb = xTb + (size_t)b * HW * 64;

  // ---- Phase A: bilinear metadata (288 tasks), offsets from global (coalesced) ----
  for (int it = tid; it < KK * TP; it += 256) {
    int kk = it >> 5;
    int px = it & 31;
    int p = p0 + px;
    int ho = p / W, wo = p - ho * W;
    float dy = off[((size_t)b * OFFC + 2 * kk) * HW + p];
    float dx = off[((size_t)b * OFFC + 2 * kk + 1) * HW + p];
    float py = dy + (float)(ho - 1 + kk / 3);
    float pxx = dx + (float)(wo - 1 + kk % 3);
    float y0f = floorf(py), x0f = floorf(pxx);
    float wy1 = py - y0f, wx1 = pxx - x0f;
    int y0 = (int)y0f, x0 = (int)x0f;
    int y1 = y0 + 1, x1 = x0 + 1;
    float vy0 = (y0 >= 0 && y0 < H) ? 1.f : 0.f;
    float vy1 = (y1 >= 0 && y1 < H) ? 1.f : 0.f;
    float vx0 = (x0 >= 0 && x0 < W) ? 1.f : 0.f;
    float vx1 = (x1 >= 0 && x1 < W) ? 1.f : 0.f;
    int cy0 = min(max(y0, 0), H - 1), cy1 = min(max(y1, 0), H - 1);
    int cx0 = min(max(x0, 0), W - 1), cx1 = min(max(x1, 0), W - 1);
    s_w[kk][px] = make_float4((1.f - wy1) * (1.f - wx1) * vy0 * vx0,
                              (1.f - wy1) * wx1 * vy0 * vx1,
                              wy1 * (1.f - wx1) * vy1 * vx0,
                              wy1 * wx1 * vy1 * vx1);
    s_ip[kk][px] = make_ushort4((ushort)(cy0 * W + cx0), (ushort)(cy0 * W + cx1),
                                (ushort)(cy1 * W + cx0), (ushort)(cy1 * W + cx1));
  }
  __syncthreads();

  int wave = tid >> 6, lane = tid & 63;
  int row16 = lane & 15, quad = lane >> 4;
  int koff = quad * 8;
  int co_base = wave * 32;
  const ushort* wa0 = w_mf + (size_t)(co_base + row16) * KDIM + koff;
  const ushort* wa1 = w_mf + (size_t)(co_base + 16 + row16) * KDIM + koff;

  floatx4 acc00 = {0.f, 0.f, 0.f, 0.f}, acc01 = acc00, acc10 = acc00, acc11 = acc00;

  for (int h = 0; h < 2; ++h) {
    // ---- Phase B: bilinear sampling (1152 tasks) with packed-f32 interp ----
#pragma unroll
    for (int r = 0; r < 5; ++r) {
      int it = tid + r * 256;
      if (it < KK * TP * 4) {
        int kk = it >> 7;                 // it = kk*128 + px*4 + cig
        int px = (it >> 2) & 31;
        int cig = it & 3;
        int cil0 = cig * 8;
        int cio = h * 32 + cil0;
        float4 wv = s_w[kk][px];
        ushort4 ip = s_ip[kk][px];
        const ushort* g0 = xb + (((int)ip.x) << 6) + cio;
        const ushort* g1 = xb + (((int)ip.y) << 6) + cio;
        const ushort* g2 = xb + (((int)ip.z) << 6) + cio;
        const ushort* g3 = xb + (((int)ip.w) << 6) + cio;
        uint4 c0 = *(const uint4*)g0;
        uint4 c1 = *(const uint4*)g1;
        uint4 c2 = *(const uint4*)g2;
        uint4 c3 = *(const uint4*)g3;
        f32x2 r0 = up2(c0.x) * wv.x + up2(c1.x) * wv.y + up2(c2.x) * wv.z + up2(c3.x) * wv.w;
        f32x2 r1 = up2(c0.y) * wv.x + up2(c1.y) * wv.y + up2(c2.y) * wv.z + up2(c3.y) * wv.w;
        f32x2 r2 = up2(c0.z) * wv.x + up2(c1.z) * wv.y + up2(c2.z) * wv.z + up2(c3.z) * wv.w;
        f32x2 r3 = up2(c0.w) * wv.x + up2(c1.w) * wv.y + up2(c2.w) * wv.z + up2(c3.w) * wv.w;
        *(uint4*)&samp[px][kk * 32 + cil0] =
            make_uint4(pack_bf2(r0.x, r0.y), pack_bf2(r1.x, r1.y),
                       pack_bf2(r2.x, r2.y), pack_bf2(r3.x, r3.y));
      }
    }
    __syncthreads();

    const ushort* sb0 = &samp[row16][koff];
    const ushort* sb1 = &samp[16 + row16][koff];
    const ushort* a0 = wa0 + h * KHALF;
    const ushort* a1 = wa1 + h * KHALF;
#pragma unroll
    for (int ks = 0; ks < 9; ++ks) {
      short8 A0 = *(const short8*)(a0 + ks * 32);
      short8 A1 = *(const short8*)(a1 + ks * 32);
      short8 B0 = *(const short8*)(sb0 + ks * 32);
      short8 B1 = *(const short8*)(sb1 + ks * 32);
      acc00 = __builtin_amdgcn_mfma_f32_16x16x32_bf16(A0, B0, acc00, 0, 0, 0);
      acc01 = __builtin_amdgcn_mfma_f32_16x16x32_bf16(A0, B1, acc01, 0, 0, 0);
      acc10 = __builtin_amdgcn_mfma_f32_16x16x32_bf16(A1, B0, acc10, 0, 0, 0);
      acc11 = __builtin_amdgcn_mfma_f32_16x16x32_bf16(A1, B1, acc11, 0, 0, 0);
    }
    __syncthreads();   // h=0: protect samp rewrite; h=1: protect yst aliasing
  }

  // ---- epilogue: stage y tile in LDS for full-line stores + atomic BN stats ----
  ushort (*yst)[YST] = (ushort(*)[YST])smem_raw;
#pragma unroll
  for (int reg = 0; reg < 4; ++reg) {
    int r0 = quad * 4 + reg;
    yst[co_base + r0][row16]            = f2bf(acc00[reg]);
    yst[co_base + r0][16 + row16]       = f2bf(acc01[reg]);
    yst[co_base + 16 + r0][row16]       = f2bf(acc10[reg]);
    yst[co_base + 16 + r0][16 + row16]  = f2bf(acc11[reg]);
  }
#pragma unroll
  for (int reg = 0; reg < 4; ++reg) {
    float s0 = acc00[reg] + acc01[reg];
    float q0 = acc00[reg] * acc00[reg] + acc01[reg] * acc01[reg];
    float s1 = acc10[reg] + acc11[reg];
    float q1 = acc10[reg] * acc10[reg] + acc11[reg] * acc11[reg];
#pragma unroll
    for (int m = 1; m < 16; m <<= 1) {
      s0 += __shfl_xor(s0, m, 64);
      q0 += __shfl_xor(q0, m, 64);
      s1 += __shfl_xor(s1, m, 64);
      q1 += __shfl_xor(q1, m, 64);
    }
    if (row16 == 0) {
      int c0 = co_base + quad * 4 + reg;
      int c1 = c0 + 16;
      atomicAdd(&stats[(size_t)c0 * SSTRIDE], s0);
      atomicAdd(&stats[(size_t)(128 + c0) * SSTRIDE], q0);
      atomicAdd(&stats[(size_t)c1 * SSTRIDE], s1);
      atomicAdd(&stats[(size_t)(128 + c1) * SSTRIDE], q1);
    }
  }
  __syncthreads();
  {
    int co = tid >> 1, hf = tid & 1;         // 2 threads per channel -> one 64B line/channel
    const ushort* src = &yst[co][hf * 16];
    uint4 v0 = *(const uint4*)src;
    uint4 v1 = *(const uint4*)(src + 8);
    ushort* dst = y + (size_t)b * COUT * HW + (size_t)co * HW + p0 + hf * 16;
    *(uint4*)dst = v0;
    *(uint4*)(dst + 8) = v1;
  }
}

// ---------------- K3: finalize stats + normalize + ReLU (y bf16 -> out fp32) ----------------
__global__ __launch_bounds__(256) void k_norm(const ushort* __restrict__ y,
                                              const float* __restrict__ stats,
                                              const float* __restrict__ gamma,
                                              const float* __restrict__ beta,
                                              float* __restrict__ out) {
  int i4 = blockIdx.x * 256 + threadIdx.x;
  const int total4 = BATCH * COUT * HW / 4;
  if (i4 >= total4) return;
  size_t i = (size_t)i4 * 4;
  int c = (int)((i / HW) & (COUT - 1));
  const float N = (float)(BATCH * HW);
  float m = stats[(size_t)c * SSTRIDE] / N;
  float var = stats[(size_t)(COUT + c) * SSTRIDE] / N - m * m;
  float r = rsqrtf(var + EPS);
  float g = gamma[c], bt = beta[c];
  uint2 u = *(const uint2*)&y[i];
  float4 v = make_float4(__uint_as_float(u.x << 16), __uint_as_float(u.x & 0xFFFF0000u),
                         __uint_as_float(u.y << 16), __uint_as_float(u.y & 0xFFFF0000u));
  v.x = fmaxf(0.f, (v.x - m) * r * g + bt);
  v.y = fmaxf(0.f, (v.y - m) * r * g + bt);
  v.z = fmaxf(0.f, (v.z - m) * r * g + bt);
  v.w = fmaxf(0.f, (v.w - m) * r * g + bt);
  *(float4*)&out[i] = v;
}

extern "C" void kernel_launch(void* const* d_in, const int* in_sizes, int n_in,
                              void* d_out, int out_size, void* d_ws, size_t ws_size,
                              hipStream_t stream) {
  const float* x     = (const float*)d_in[0];
  const float* w_off = (const float*)d_in[1];
  const float* b_off = (const float*)d_in[2];
  const float* w_dcn = (const float*)d_in[3];
  // d_in[4] = b_dcn: cancels exactly through batch-norm
  const float* gamma = (const float*)d_in[5];
  const float* beta  = (const float*)d_in[6];
  float* out = (float*)d_out;

  float* ws = (float*)d_ws;
  float*  off_buf = ws;                                   // 1,806,336 floats
  float*  stats   = off_buf + 1806336;                    //     4,096 (64B-padded)
  ushort* xTb     = (ushort*)(stats + 256 * SSTRIDE);     // 6,422,528 ushorts
  ushort* w_mf    = xTb + (size_t)BATCH * HW * 64;        //    73,728
  ushort* w_offT  = w_mf + COUT * KDIM;                   //    18,432
  ushort* y_bf    = w_offT + 32 * KDIM;                   // 12,845,056 ushorts
  // total ~46 MB

  k_prep<<<dim3(196, 9), 256, 0, stream>>>(x, w_off, w_dcn, xTb, w_offT, w_mf, stats);
  k_offset_conv<<<dim3(HW / 64, BATCH), 256, 0, stream>>>(xTb, w_offT, b_off, off_buf);
  k_deform<<<dim3(HW / TP, BATCH), 256, 0, stream>>>(xTb, off_buf, w_mf, y_bf, stats);
  k_norm<<<BATCH * COUT * HW / 4 / 256, 256, 0, stream>>>(y_bf, stats, gamma, beta, out);
}

// Round 4
// 251.191 us; speedup vs baseline: 1.0312x; 1.0312x over previous
//
#include <hip/hip_runtime.h>

#define H    112
#define W    112
#define HW   12544
#define CIN  64
#define COUT 128
#define BATCH 8
#define KK   9
#define OFFC 18
#define EPS  1e-5f
#define TP   32      // pixels per deform block
#define KDIM 576     // CIN*KK
#define KHALF 288    // K split in two passes
#define KPAD2 296    // samp row stride (elements): 148 dwords -> good bank spread
#define NB   3136    // deform grid size (HW/TP * BATCH)
#define YST  40      // y staging row stride (ushorts): 20 dwords -> spread
#define SSTRIDE 16   // stats padding: one float per 64B line

typedef unsigned short ushort;
typedef unsigned int uint;
typedef __attribute__((ext_vector_type(8))) short short8;
typedef __attribute__((ext_vector_type(4))) float floatx4;
typedef __attribute__((ext_vector_type(2))) float f32x2;

__device__ __forceinline__ ushort f2bf(float f) {
  uint u = __float_as_uint(f);
  u = (u + 0x7FFFu + ((u >> 16) & 1u)) >> 16;   // RNE
  return (ushort)u;
}

// pack two fp32 -> two bf16 (RNE-ish) in one v_perm
__device__ __forceinline__ uint pack_bf2(float f0, float f1) {
  uint u0 = __float_as_uint(f0) + 0x8000u;
  uint u1 = __float_as_uint(f1) + 0x8000u;
  return __builtin_amdgcn_perm(u1, u0, 0x07060302u);
}

// unpack a dword of 2 bf16 -> f32x2
__device__ __forceinline__ f32x2 up2(uint u) {
  f32x2 r;
  r.x = __uint_as_float(u << 16);
  r.y = __uint_as_float(u & 0xFFFF0000u);
  return r;
}

// ---------------- K0: transpose x -> xTb bf16 [B][HW][CIN] + weight prep + stats zero ----------------
__global__ __launch_bounds__(256) void k_prep(
    const float* __restrict__ x, const float* __restrict__ w_off,
    const float* __restrict__ w_dcn, ushort* __restrict__ xTb,
    ushort* __restrict__ w_offT, ushort* __restrict__ w_mf,
    float* __restrict__ stats) {
  if (blockIdx.y < BATCH) {
    __shared__ float tile[64][65];
    int b = blockIdx.y;
    int p0 = blockIdx.x * 64;
    int tid = threadIdx.x;
    int j = tid & 63, cb = tid >> 6;
#pragma unroll
    for (int i = 0; i < 16; ++i) {
      int ci = cb * 16 + i;
      tile[ci][j] = x[((size_t)(b * CIN + ci)) * HW + p0 + j];
    }
    __syncthreads();
    int px = tid >> 2, ciq = tid & 3;
#pragma unroll
    for (int g = 0; g < 4; ++g) {
      int ci = ciq * 16 + g * 4;
      uint lo = pack_bf2(tile[ci + 0][px], tile[ci + 1][px]);
      uint hi = pack_bf2(tile[ci + 2][px], tile[ci + 3][px]);
      *(uint2*)&xTb[((size_t)b * HW + p0 + px) * 64 + ci] = make_uint2(lo, hi);
    }
  } else {
    int tid = threadIdx.x;
    if (blockIdx.x == 0) {   // zero padded stats (stream-ordered before k_reduce atomics)
#pragma unroll
      for (int i = tid; i < 256 * SSTRIDE; i += 256) stats[i] = 0.f;
    }
    // weight prep: w_offT[oc<32][kk*64+ci], w_mf[co][h*288 + kk*32 + cil]
    const int TOT = 32 * KDIM + COUT * KDIM;
    for (int i = blockIdx.x * 256 + tid; i < TOT; i += 196 * 256) {
      if (i < 32 * KDIM) {
        int oc = i / KDIM, k = i - oc * KDIM;
        int kk = k >> 6, ci = k & 63;
        float v = (oc < OFFC) ? w_off[(oc * CIN + ci) * KK + kk] : 0.f;
        w_offT[i] = f2bf(v);
      } else {
        int jj = i - 32 * KDIM;
        int co = jj / KDIM, k = jj - co * KDIM;
        int h2 = k / KHALF, r = k - h2 * KHALF;
        int kk = r >> 5, cil = r & 31;
        int ci = h2 * 32 + cil;
        w_mf[jj] = f2bf(w_dcn[(co * CIN + ci) * KK + kk]);
      }
    }
  }
}

// ---------------- K1: offset conv as register-resident bf16 MFMA (standalone: latency hides) ----------------
__global__ __launch_bounds__(256) void k_offset_conv(
    const ushort* __restrict__ xTb, const ushort* __restrict__ w_offT,
    const float* __restrict__ bias, float* __restrict__ out) {
  int b = blockIdx.y;
  int wave = threadIdx.x >> 6, lane = threadIdx.x & 63;
  int row16 = lane & 15, quad = lane >> 4;
  int p = blockIdx.x * 64 + wave * 16 + row16;
  int ho = p / W, wo = p - ho * W;
  const ushort* xb = xTb + (size_t)b * HW * 64;

  short8 Bf[18];
#pragma unroll
  for (int ks = 0; ks < 18; ++ks) {
    int kk = ks >> 1;
    int ci0 = (ks & 1) * 32 + quad * 8;
    int kh = kk / 3, kw = kk - kh * 3;
    int yy = ho + kh - 1, xx = wo + kw - 1;
    bool valid = (yy >= 0) & (yy < H) & (xx >= 0) & (xx < W);
    short8 v = {0, 0, 0, 0, 0, 0, 0, 0};
    if (valid) v = *(const short8*)(xb + ((size_t)(yy * W + xx) << 6) + ci0);
    Bf[ks] = v;
  }
  floatx4 acc0 = {0.f, 0.f, 0.f, 0.f}, acc1 = acc0;
  const ushort* wa0 = w_offT + row16 * KDIM + quad * 8;
  const ushort* wa1 = w_offT + (16 + row16) * KDIM + quad * 8;
#pragma unroll
  for (int ks = 0; ks < 18; ++ks) {
    short8 A0 = *(const short8*)(wa0 + ks * 32);
    short8 A1 = *(const short8*)(wa1 + ks * 32);
    acc0 = __builtin_amdgcn_mfma_f32_16x16x32_bf16(A0, Bf[ks], acc0, 0, 0, 0);
    acc1 = __builtin_amdgcn_mfma_f32_16x16x32_bf16(A1, Bf[ks], acc1, 0, 0, 0);
  }
  float* ob = out + (size_t)b * OFFC * HW;
#pragma unroll
  for (int reg = 0; reg < 4; ++reg) {
    int oc = quad * 4 + reg;
    ob[(size_t)oc * HW + p] = acc0[reg] + bias[oc];
    int oc1 = 16 + oc;
    if (oc1 < OFFC) ob[(size_t)oc1 * HW + p] = acc1[reg] + bias[oc1];
  }
}

// ---------------- K2: deform conv (K-split bf16 MFMA) -> y bf16 + per-block BN partials ----------------
__global__ __launch_bounds__(256, 6) void k_deform(
    const ushort* __restrict__ xTb, const float* __restrict__ off,
    const ushort* __restrict__ w_mf, ushort* __restrict__ y,
    float* __restrict__ psT) {
  __shared__ float4  s_w[KK][TP];                          // 4608 B
  __shared__ ushort4 s_ip[KK][TP];                         // 2304 B (pixel indices, <<6 at use)
  __shared__ __align__(16) char smem_raw[TP * KPAD2 * 2];  // 18944 B: samp -> yst
  ushort (*samp)[KPAD2] = (ushort(*)[KPAD2])smem_raw;

  int b = blockIdx.y;
  int p0 = blockIdx.x * TP;
  int bid = blockIdx.y * gridDim.x + blockIdx.x;
  int tid = threadIdx.x;
  const ushort* xb = xTb + (size_t)b * HW * 64;

  // ---- Phase A: bilinear metadata (288 tasks), offsets from global (coalesced) ----
  for (int it = tid; it < KK * TP; it += 256) {
    int kk = it >> 5;
    int px = it & 31;
    int p = p0 + px;
    int ho = p / W, wo = p - ho * W;
    float dy = off[((size_t)b * OFFC + 2 * kk) * HW + p];
    float dx = off[((size_t)b * OFFC + 2 * kk + 1) * HW + p];
    float py = dy + (float)(ho - 1 + kk / 3);
    float pxx = dx + (float)(wo - 1 + kk % 3);
    float y0f = floorf(py), x0f = floorf(pxx);
    float wy1 = py - y0f, wx1 = pxx - x0f;
    int y0 = (int)y0f, x0 = (int)x0f;
    int y1 = y0 + 1, x1 = x0 + 1;
    float vy0 = (y0 >= 0 && y0 < H) ? 1.f : 0.f;
    float vy1 = (y1 >= 0 && y1 < H) ? 1.f : 0.f;
    float vx0 = (x0 >= 0 && x0 < W) ? 1.f : 0.f;
    float vx1 = (x1 >= 0 && x1 < W) ? 1.f : 0.f;
    int cy0 = min(max(y0, 0), H - 1), cy1 = min(max(y1, 0), H - 1);
    int cx0 = min(max(x0, 0), W - 1), cx1 = min(max(x1, 0), W - 1);
    s_w[kk][px] = make_float4((1.f - wy1) * (1.f - wx1) * vy0 * vx0,
                              (1.f - wy1) * wx1 * vy0 * vx1,
                              wy1 * (1.f - wx1) * vy1 * vx0,
                              wy1 * wx1 * vy1 * vx1);
    s_ip[kk][px] = make_ushort4((ushort)(cy0 * W + cx0), (ushort)(cy0 * W + cx1),
                                (ushort)(cy1 * W + cx0), (ushort)(cy1 * W + cx1));
  }
  __syncthreads();

  int wave = tid >> 6, lane = tid & 63;
  int row16 = lane & 15, quad = lane >> 4;
  int koff = quad * 8;
  int co_base = wave * 32;
  const ushort* wa0 = w_mf + (size_t)(co_base + row16) * KDIM + koff;
  const ushort* wa1 = w_mf + (size_t)(co_base + 16 + row16) * KDIM + koff;

  floatx4 acc00 = {0.f, 0.f, 0.f, 0.f}, acc01 = acc00, acc10 = acc00, acc11 = acc00;

  for (int h = 0; h < 2; ++h) {
    // ---- Phase B: bilinear sampling (1152 tasks) with packed-f32 interp ----
#pragma unroll
    for (int r = 0; r < 5; ++r) {
      int it = tid + r * 256;
      if (it < KK * TP * 4) {
        int kk = it >> 7;                 // it = kk*128 + px*4 + cig
        int px = (it >> 2) & 31;
        int cig = it & 3;
        int cil0 = cig * 8;
        int cio = h * 32 + cil0;
        float4 wv = s_w[kk][px];
        ushort4 ip = s_ip[kk][px];
        const ushort* g0 = xb + (((int)ip.x) << 6) + cio;
        const ushort* g1 = xb + (((int)ip.y) << 6) + cio;
        const ushort* g2 = xb + (((int)ip.z) << 6) + cio;
        const ushort* g3 = xb + (((int)ip.w) << 6) + cio;
        uint4 c0 = *(const uint4*)g0;
        uint4 c1 = *(const uint4*)g1;
        uint4 c2 = *(const uint4*)g2;
        uint4 c3 = *(const uint4*)g3;
        f32x2 r0 = up2(c0.x) * wv.x + up2(c1.x) * wv.y + up2(c2.x) * wv.z + up2(c3.x) * wv.w;
        f32x2 r1 = up2(c0.y) * wv.x + up2(c1.y) * wv.y + up2(c2.y) * wv.z + up2(c3.y) * wv.w;
        f32x2 r2 = up2(c0.z) * wv.x + up2(c1.z) * wv.y + up2(c2.z) * wv.z + up2(c3.z) * wv.w;
        f32x2 r3 = up2(c0.w) * wv.x + up2(c1.w) * wv.y + up2(c2.w) * wv.z + up2(c3.w) * wv.w;
        *(uint4*)&samp[px][kk * 32 + cil0] =
            make_uint4(pack_bf2(r0.x, r0.y), pack_bf2(r1.x, r1.y),
                       pack_bf2(r2.x, r2.y), pack_bf2(r3.x, r3.y));
      }
    }
    __syncthreads();

    const ushort* sb0 = &samp[row16][koff];
    const ushort* sb1 = &samp[16 + row16][koff];
    const ushort* a0 = wa0 + h * KHALF;
    const ushort* a1 = wa1 + h * KHALF;
#pragma unroll
    for (int ks = 0; ks < 9; ++ks) {
      short8 A0 = *(const short8*)(a0 + ks * 32);
      short8 A1 = *(const short8*)(a1 + ks * 32);
      short8 B0 = *(const short8*)(sb0 + ks * 32);
      short8 B1 = *(const short8*)(sb1 + ks * 32);
      acc00 = __builtin_amdgcn_mfma_f32_16x16x32_bf16(A0, B0, acc00, 0, 0, 0);
      acc01 = __builtin_amdgcn_mfma_f32_16x16x32_bf16(A0, B1, acc01, 0, 0, 0);
      acc10 = __builtin_amdgcn_mfma_f32_16x16x32_bf16(A1, B0, acc10, 0, 0, 0);
      acc11 = __builtin_amdgcn_mfma_f32_16x16x32_bf16(A1, B1, acc11, 0, 0, 0);
    }
    __syncthreads();   // h=0: protect samp rewrite; h=1: protect yst aliasing
  }

  // ---- epilogue: stage y tile in LDS for full-line stores + contiguous BN partials ----
  ushort (*yst)[YST] = (ushort(*)[YST])smem_raw;
#pragma unroll
  for (int reg = 0; reg < 4; ++reg) {
    int r0 = quad * 4 + reg;
    yst[co_base + r0][row16]            = f2bf(acc00[reg]);
    yst[co_base + r0][16 + row16]       = f2bf(acc01[reg]);
    yst[co_base + 16 + r0][row16]       = f2bf(acc10[reg]);
    yst[co_base + 16 + r0][16 + row16]  = f2bf(acc11[reg]);
  }
#pragma unroll
  for (int reg = 0; reg < 4; ++reg) {
    float s0 = acc00[reg] + acc01[reg];
    float q0 = acc00[reg] * acc00[reg] + acc01[reg] * acc01[reg];
    float s1 = acc10[reg] + acc11[reg];
    float q1 = acc10[reg] * acc10[reg] + acc11[reg] * acc11[reg];
#pragma unroll
    for (int m = 1; m < 16; m <<= 1) {
      s0 += __shfl_xor(s0, m, 64);
      q0 += __shfl_xor(q0, m, 64);
      s1 += __shfl_xor(s1, m, 64);
      q1 += __shfl_xor(q1, m, 64);
    }
    if (row16 == 0) {
      int c0 = co_base + quad * 4 + reg;
      float* pb = psT + (size_t)bid * 256;   // contiguous 1 KB per block, no contention
      pb[c0] = s0;
      pb[COUT + c0] = q0;
      pb[c0 + 16] = s1;
      pb[COUT + c0 + 16] = q1;
    }
  }
  __syncthreads();
  {
    int co = tid >> 1, hf = tid & 1;         // 2 threads per channel -> one 64B line/channel
    const ushort* src = &yst[co][hf * 16];
    uint4 v0 = *(const uint4*)src;
    uint4 v1 = *(const uint4*)(src + 8);
    ushort* dst = y + (size_t)b * COUT * HW + (size_t)co * HW + p0 + hf * 16;
    *(uint4*)dst = v0;
    *(uint4*)(dst + 8) = v1;
  }
}

// ---------------- K3: coalesced reduce psT[NB][256] -> stats (8K spread atomics) ----------------
__global__ __launch_bounds__(256) void k_reduce(const float* __restrict__ psT,
                                                float* __restrict__ stats) {
  int c = threadIdx.x;
  float s = 0.f;
  for (int r = blockIdx.x; r < NB; r += gridDim.x)
    s += psT[(size_t)r * 256 + c];
  atomicAdd(&stats[(size_t)c * SSTRIDE], s);
}

// ---------------- K4: finalize stats + normalize + ReLU (y bf16 -> out fp32) ----------------
__global__ __launch_bounds__(256) void k_norm(const ushort* __restrict__ y,
                                              const float* __restrict__ stats,
                                              const float* __restrict__ gamma,
                                              const float* __restrict__ beta,
                                              float* __restrict__ out) {
  int i4 = blockIdx.x * 256 + threadIdx.x;
  const int total4 = BATCH * COUT * HW / 4;
  if (i4 >= total4) return;
  size_t i = (size_t)i4 * 4;
  int c = (int)((i / HW) & (COUT - 1));
  const float N = (float)(BATCH * HW);
  float m = stats[(size_t)c * SSTRIDE] / N;
  float var = stats[(size_t)(COUT + c) * SSTRIDE] / N - m * m;
  float r = rsqrtf(var + EPS);
  float g = gamma[c], bt = beta[c];
  uint2 u = *(const uint2*)&y[i];
  float4 v = make_float4(__uint_as_float(u.x << 16), __uint_as_float(u.x & 0xFFFF0000u),
                         __uint_as_float(u.y << 16), __uint_as_float(u.y & 0xFFFF0000u));
  v.x = fmaxf(0.f, (v.x - m) * r * g + bt);
  v.y = fmaxf(0.f, (v.y - m) * r * g + bt);
  v.z = fmaxf(0.f, (v.z - m) * r * g + bt);
  v.w = fmaxf(0.f, (v.w - m) * r * g + bt);
  *(float4*)&out[i] = v;
}

extern "C" void kernel_launch(void* const* d_in, const int* in_sizes, int n_in,
                              void* d_out, int out_size, void* d_ws, size_t ws_size,
                              hipStream_t stream) {
  const float* x     = (const float*)d_in[0];
  const float* w_off = (const float*)d_in[1];
  const float* b_off = (const float*)d_in[2];
  const float* w_dcn = (const float*)d_in[3];
  // d_in[4] = b_dcn: cancels exactly through batch-norm
  const float* gamma = (const float*)d_in[5];
  const float* beta  = (const float*)d_in[6];
  float* out = (float*)d_out;

  float* ws = (float*)d_ws;
  float*  off_buf = ws;                                   // 1,806,336 floats
  float*  psT     = off_buf + 1806336;                    //   802,816 floats
  float*  stats   = psT + 802816;                         //     4,096 (64B-padded)
  ushort* xTb     = (ushort*)(stats + 256 * SSTRIDE);     // 6,422,528 ushorts
  ushort* w_mf    = xTb + (size_t)BATCH * HW * 64;        //    73,728
  ushort* w_offT  = w_mf + COUT * KDIM;                   //    18,432
  ushort* y_bf    = w_offT + 32 * KDIM;                   // 12,845,056 ushorts
  // total ~49 MB

  k_prep<<<dim3(196, 9), 256, 0, stream>>>(x, w_off, w_dcn, xTb, w_offT, w_mf, stats);
  k_offset_conv<<<dim3(HW / 64, BATCH), 256, 0, stream>>>(xTb, w_offT, b_off, off_buf);
  k_deform<<<dim3(HW / TP, BATCH), 256, 0, stream>>>(xTb, off_buf, w_mf, y_bf, psT);
  k_reduce<<<32, 256, 0, stream>>>(psT, stats);
  k_norm<<<BATCH * COUT * HW / 4 / 256, 256, 0, stream>>>(y_bf, stats, gamma, beta, out);
}

// Round 5
// 248.290 us; speedup vs baseline: 1.0433x; 1.0117x over previous
//
#include <hip/hip_runtime.h>

#define H    112
#define W    112
#define HW   12544
#define CIN  64
#define COUT 128
#define BATCH 8
#define KK   9
#define OFFC 18
#define EPS  1e-5f
#define TP   32      // pixels per deform block
#define KDIM 576     // CIN*KK
#define KHALF 288    // K split in two passes
#define KPAD2 296    // samp row stride (elements): 148 dwords -> good bank spread
#define NB   3136    // deform grid size (HW/TP * BATCH)
#define YST  40      // y staging row stride (ushorts): 20 dwords -> spread
#define SSTRIDE 16   // stats padding: one float per 64B line

typedef unsigned short ushort;
typedef unsigned int uint;
typedef __attribute__((ext_vector_type(8))) short short8;
typedef __attribute__((ext_vector_type(4))) float floatx4;
typedef __attribute__((ext_vector_type(2))) float f32x2;

__device__ __forceinline__ ushort f2bf(float f) {
  uint u = __float_as_uint(f);
  u = (u + 0x7FFFu + ((u >> 16) & 1u)) >> 16;   // RNE
  return (ushort)u;
}

// pack two fp32 -> two bf16 (RNE-ish) in one v_perm
__device__ __forceinline__ uint pack_bf2(float f0, float f1) {
  uint u0 = __float_as_uint(f0) + 0x8000u;
  uint u1 = __float_as_uint(f1) + 0x8000u;
  return __builtin_amdgcn_perm(u1, u0, 0x07060302u);
}

// unpack a dword of 2 bf16 -> f32x2
__device__ __forceinline__ f32x2 up2(uint u) {
  f32x2 r;
  r.x = __uint_as_float(u << 16);
  r.y = __uint_as_float(u & 0xFFFF0000u);
  return r;
}

// XCD-band swizzle for 196-tile grids (196 = 8*24 + 4): bijective
__device__ __forceinline__ int tile196(int bx) {
  int xcd = bx & 7, q = bx >> 3;
  return (xcd < 4) ? xcd * 25 + q : 100 + (xcd - 4) * 24 + q;
}

// ---------------- K0: transpose x -> xTb bf16 [B][HW][CIN] + weight prep + stats zero ----------------
__global__ __launch_bounds__(256) void k_prep(
    const float* __restrict__ x, const float* __restrict__ w_off,
    const float* __restrict__ w_dcn, ushort* __restrict__ xTb,
    ushort* __restrict__ w_offT, ushort* __restrict__ w_mf,
    float* __restrict__ stats) {
  if (blockIdx.y < BATCH) {
    __shared__ float tile[64][65];
    int b = blockIdx.y;
    int p0 = tile196(blockIdx.x) * 64;   // same XCD band as the consumers
    int tid = threadIdx.x;
    int j = tid & 63, cb = tid >> 6;
#pragma unroll
    for (int i = 0; i < 16; ++i) {
      int ci = cb * 16 + i;
      tile[ci][j] = x[((size_t)(b * CIN + ci)) * HW + p0 + j];
    }
    __syncthreads();
    int px = tid >> 2, ciq = tid & 3;
#pragma unroll
    for (int g = 0; g < 4; ++g) {
      int ci = ciq * 16 + g * 4;
      uint lo = pack_bf2(tile[ci + 0][px], tile[ci + 1][px]);
      uint hi = pack_bf2(tile[ci + 2][px], tile[ci + 3][px]);
      *(uint2*)&xTb[((size_t)b * HW + p0 + px) * 64 + ci] = make_uint2(lo, hi);
    }
  } else {
    int tid = threadIdx.x;
    if (blockIdx.x == 0) {   // zero padded stats (stream-ordered before k_reduce atomics)
#pragma unroll
      for (int i = tid; i < 256 * SSTRIDE; i += 256) stats[i] = 0.f;
    }
    // weight prep: w_offT[oc<32][kk*64+ci], w_mf[co][h*288 + kk*32 + cil]
    const int TOT = 32 * KDIM + COUT * KDIM;
    for (int i = blockIdx.x * 256 + tid; i < TOT; i += 196 * 256) {
      if (i < 32 * KDIM) {
        int oc = i / KDIM, k = i - oc * KDIM;
        int kk = k >> 6, ci = k & 63;
        float v = (oc < OFFC) ? w_off[(oc * CIN + ci) * KK + kk] : 0.f;
        w_offT[i] = f2bf(v);
      } else {
        int jj = i - 32 * KDIM;
        int co = jj / KDIM, k = jj - co * KDIM;
        int h2 = k / KHALF, r = k - h2 * KHALF;
        int kk = r >> 5, cil = r & 31;
        int ci = h2 * 32 + cil;
        w_mf[jj] = f2bf(w_dcn[(co * CIN + ci) * KK + kk]);
      }
    }
  }
}

// ---------------- K1: offset conv as register-resident bf16 MFMA ----------------
__global__ __launch_bounds__(256) void k_offset_conv(
    const ushort* __restrict__ xTb, const ushort* __restrict__ w_offT,
    const float* __restrict__ bias, float* __restrict__ out) {
  int b = blockIdx.y;
  int wave = threadIdx.x >> 6, lane = threadIdx.x & 63;
  int row16 = lane & 15, quad = lane >> 4;
  int p = tile196(blockIdx.x) * 64 + wave * 16 + row16;   // XCD band swizzle
  int ho = p / W, wo = p - ho * W;
  const ushort* xb = xTb + (size_t)b * HW * 64;

  short8 Bf[18];
#pragma unroll
  for (int ks = 0; ks < 18; ++ks) {
    int kk = ks >> 1;
    int ci0 = (ks & 1) * 32 + quad * 8;
    int kh = kk / 3, kw = kk - kh * 3;
    int yy = ho + kh - 1, xx = wo + kw - 1;
    bool valid = (yy >= 0) & (yy < H) & (xx >= 0) & (xx < W);
    short8 v = {0, 0, 0, 0, 0, 0, 0, 0};
    if (valid) v = *(const short8*)(xb + ((size_t)(yy * W + xx) << 6) + ci0);
    Bf[ks] = v;
  }
  floatx4 acc0 = {0.f, 0.f, 0.f, 0.f}, acc1 = acc0;
  const ushort* wa0 = w_offT + row16 * KDIM + quad * 8;
  const ushort* wa1 = w_offT + (16 + row16) * KDIM + quad * 8;
#pragma unroll
  for (int ks = 0; ks < 18; ++ks) {
    short8 A0 = *(const short8*)(wa0 + ks * 32);
    short8 A1 = *(const short8*)(wa1 + ks * 32);
    acc0 = __builtin_amdgcn_mfma_f32_16x16x32_bf16(A0, Bf[ks], acc0, 0, 0, 0);
    acc1 = __builtin_amdgcn_mfma_f32_16x16x32_bf16(A1, Bf[ks], acc1, 0, 0, 0);
  }
  float* ob = out + (size_t)b * OFFC * HW;
#pragma unroll
  for (int reg = 0; reg < 4; ++reg) {
    int oc = quad * 4 + reg;
    ob[(size_t)oc * HW + p] = acc0[reg] + bias[oc];
    int oc1 = 16 + oc;
    if (oc1 < OFFC) ob[(size_t)oc1 * HW + p] = acc1[reg] + bias[oc1];
  }
}

// ---------------- K2: deform conv (K-split bf16 MFMA) -> y bf16 + per-block BN partials ----------------
__global__ __launch_bounds__(256, 6) void k_deform(
    const ushort* __restrict__ xTb, const float* __restrict__ off,
    const ushort* __restrict__ w_mf, ushort* __restrict__ y,
    float* __restrict__ psT) {
  __shared__ float4  s_w[KK][TP];                          // 4608 B
  __shared__ ushort4 s_ip[KK][TP];                         // 2304 B (pixel indices, <<6 at use)
  __shared__ __align__(16) char smem_raw[TP * KPAD2 * 2];  // 18944 B: samp -> yst
  ushort (*samp)[KPAD2] = (ushort(*)[KPAD2])smem_raw;

  int b = blockIdx.y;
  // XCD-band swizzle: 392 tiles = 8 XCDs x 49 contiguous tiles (~14 image rows each).
  // Linear-id round-robin + 392%8==0 makes the mapping batch-invariant, so each
  // XCD's L2 holds the same ~1.8 MB xTb band across all 8 batches.
  int tile = ((blockIdx.x & 7) * 49) + (blockIdx.x >> 3);
  int p0 = tile * TP;
  int bid = blockIdx.y * gridDim.x + tile;
  int tid = threadIdx.x;
  const ushort* xb = xTb + (size_t)b * HW * 64;

  // ---- Phase A: bilinear metadata (288 tasks), offsets from global (coalesced) ----
  for (int it = tid; it < KK * TP; it += 256) {
    int kk = it >> 5;
    int px = it & 31;
    int p = p0 + px;
    int ho = p / W, wo = p - ho * W;
    float dy = off[((size_t)b * OFFC + 2 * kk) * HW + p];
    float dx = off[((size_t)b * OFFC + 2 * kk + 1) * HW + p];
    float py = dy + (float)(ho - 1 + kk / 3);
    float pxx = dx + (float)(wo - 1 + kk % 3);
    float y0f = floorf(py), x0f = floorf(pxx);
    float wy1 = py - y0f, wx1 = pxx - x0f;
    int y0 = (int)y0f, x0 = (int)x0f;
    int y1 = y0 + 1, x1 = x0 + 1;
    float vy0 = (y0 >= 0 && y0 < H) ? 1.f : 0.f;
    float vy1 = (y1 >= 0 && y1 < H) ? 1.f : 0.f;
    float vx0 = (x0 >= 0 && x0 < W) ? 1.f : 0.f;
    float vx1 = (x1 >= 0 && x1 < W) ? 1.f : 0.f;
    int cy0 = min(max(y0, 0), H - 1), cy1 = min(max(y1, 0), H - 1);
    int cx0 = min(max(x0, 0), W - 1), cx1 = min(max(x1, 0), W - 1);
    s_w[kk][px] = make_float4((1.f - wy1) * (1.f - wx1) * vy0 * vx0,
                              (1.f - wy1) * wx1 * vy0 * vx1,
                              wy1 * (1.f - wx1) * vy1 * vx0,
                              wy1 * wx1 * vy1 * vx1);
    s_ip[kk][px] = make_ushort4((ushort)(cy0 * W + cx0), (ushort)(cy0 * W + cx1),
                                (ushort)(cy1 * W + cx0), (ushort)(cy1 * W + cx1));
  }
  __syncthreads();

  int wave = tid >> 6, lane = tid & 63;
  int row16 = lane & 15, quad = lane >> 4;
  int koff = quad * 8;
  int co_base = wave * 32;
  const ushort* wa0 = w_mf + (size_t)(co_base + row16) * KDIM + koff;
  const ushort* wa1 = w_mf + (size_t)(co_base + 16 + row16) * KDIM + koff;

  floatx4 acc00 = {0.f, 0.f, 0.f, 0.f}, acc01 = acc00, acc10 = acc00, acc11 = acc00;

  for (int h = 0; h < 2; ++h) {
    // ---- Phase B: bilinear sampling (1152 tasks) with packed-f32 interp ----
#pragma unroll
    for (int r = 0; r < 5; ++r) {
      int it = tid + r * 256;
      if (it < KK * TP * 4) {
        int kk = it >> 7;                 // it = kk*128 + px*4 + cig
        int px = (it >> 2) & 31;
        int cig = it & 3;
        int cil0 = cig * 8;
        int cio = h * 32 + cil0;
        float4 wv = s_w[kk][px];
        ushort4 ip = s_ip[kk][px];
        const ushort* g0 = xb + (((int)ip.x) << 6) + cio;
        const ushort* g1 = xb + (((int)ip.y) << 6) + cio;
        const ushort* g2 = xb + (((int)ip.z) << 6) + cio;
        const ushort* g3 = xb + (((int)ip.w) << 6) + cio;
        uint4 c0 = *(const uint4*)g0;
        uint4 c1 = *(const uint4*)g1;
        uint4 c2 = *(const uint4*)g2;
        uint4 c3 = *(const uint4*)g3;
        f32x2 r0 = up2(c0.x) * wv.x + up2(c1.x) * wv.y + up2(c2.x) * wv.z + up2(c3.x) * wv.w;
        f32x2 r1 = up2(c0.y) * wv.x + up2(c1.y) * wv.y + up2(c2.y) * wv.z + up2(c3.y) * wv.w;
        f32x2 r2 = up2(c0.z) * wv.x + up2(c1.z) * wv.y + up2(c2.z) * wv.z + up2(c3.z) * wv.w;
        f32x2 r3 = up2(c0.w) * wv.x + up2(c1.w) * wv.y + up2(c2.w) * wv.z + up2(c3.w) * wv.w;
        *(uint4*)&samp[px][kk * 32 + cil0] =
            make_uint4(pack_bf2(r0.x, r0.y), pack_bf2(r1.x, r1.y),
                       pack_bf2(r2.x, r2.y), pack_bf2(r3.x, r3.y));
      }
    }
    __syncthreads();

    const ushort* sb0 = &samp[row16][koff];
    const ushort* sb1 = &samp[16 + row16][koff];
    const ushort* a0 = wa0 + h * KHALF;
    const ushort* a1 = wa1 + h * KHALF;
#pragma unroll
    for (int ks = 0; ks < 9; ++ks) {
      short8 A0 = *(const short8*)(a0 + ks * 32);
      short8 A1 = *(const short8*)(a1 + ks * 32);
      short8 B0 = *(const short8*)(sb0 + ks * 32);
      short8 B1 = *(const short8*)(sb1 + ks * 32);
      acc00 = __builtin_amdgcn_mfma_f32_16x16x32_bf16(A0, B0, acc00, 0, 0, 0);
      acc01 = __builtin_amdgcn_mfma_f32_16x16x32_bf16(A0, B1, acc01, 0, 0, 0);
      acc10 = __builtin_amdgcn_mfma_f32_16x16x32_bf16(A1, B0, acc10, 0, 0, 0);
      acc11 = __builtin_amdgcn_mfma_f32_16x16x32_bf16(A1, B1, acc11, 0, 0, 0);
    }
    __syncthreads();   // h=0: protect samp rewrite; h=1: protect yst aliasing
  }

  // ---- epilogue: stage y tile in LDS for full-line stores + contiguous BN partials ----
  ushort (*yst)[YST] = (ushort(*)[YST])smem_raw;
#pragma unroll
  for (int reg = 0; reg < 4; ++reg) {
    int r0 = quad * 4 + reg;
    yst[co_base + r0][row16]            = f2bf(acc00[reg]);
    yst[co_base + r0][16 + row16]       = f2bf(acc01[reg]);
    yst[co_base + 16 + r0][row16]       = f2bf(acc10[reg]);
    yst[co_base + 16 + r0][16 + row16]  = f2bf(acc11[reg]);
  }
#pragma unroll
  for (int reg = 0; reg < 4; ++reg) {
    float s0 = acc00[reg] + acc01[reg];
    float q0 = acc00[reg] * acc00[reg] + acc01[reg] * acc01[reg];
    float s1 = acc10[reg] + acc11[reg];
    float q1 = acc10[reg] * acc10[reg] + acc11[reg] * acc11[reg];
#pragma unroll
    for (int m = 1; m < 16; m <<= 1) {
      s0 += __shfl_xor(s0, m, 64);
      q0 += __shfl_xor(q0, m, 64);
      s1 += __shfl_xor(s1, m, 64);
      q1 += __shfl_xor(q1, m, 64);
    }
    if (row16 == 0) {
      int c0 = co_base + quad * 4 + reg;
      float* pb = psT + (size_t)bid * 256;   // contiguous 1 KB per block, no contention
      pb[c0] = s0;
      pb[COUT + c0] = q0;
      pb[c0 + 16] = s1;
      pb[COUT + c0 + 16] = q1;
    }
  }
  __syncthreads();
  {
    int co = tid >> 1, hf = tid & 1;         // 2 threads per channel -> one 64B line/channel
    const ushort* src = &yst[co][hf * 16];
    uint4 v0 = *(const uint4*)src;
    uint4 v1 = *(const uint4*)(src + 8);
    ushort* dst = y + (size_t)b * COUT * HW + (size_t)co * HW + p0 + hf * 16;
    *(uint4*)dst = v0;
    *(uint4*)(dst + 8) = v1;
  }
}

// ---------------- K3: coalesced reduce psT[NB][256] -> stats (8K spread atomics) ----------------
__global__ __launch_bounds__(256) void k_reduce(const float* __restrict__ psT,
                                                float* __restrict__ stats) {
  int c = threadIdx.x;
  float s = 0.f;
  for (int r = blockIdx.x; r < NB; r += gridDim.x)
    s += psT[(size_t)r * 256 + c];
  atomicAdd(&stats[(size_t)c * SSTRIDE], s);
}

// ---------------- K4: finalize stats + normalize + ReLU (y bf16 -> out fp32) ----------------
__global__ __launch_bounds__(256) void k_norm(const ushort* __restrict__ y,
                                              const float* __restrict__ stats,
                                              const float* __restrict__ gamma,
                                              const float* __restrict__ beta,
                                              float* __restrict__ out) {
  int i4 = blockIdx.x * 256 + threadIdx.x;
  const int total4 = BATCH * COUT * HW / 4;
  if (i4 >= total4) return;
  size_t i = (size_t)i4 * 4;
  int c = (int)((i / HW) & (COUT - 1));
  const float N = (float)(BATCH * HW);
  float m = stats[(size_t)c * SSTRIDE] / N;
  float var = stats[(size_t)(COUT + c) * SSTRIDE] / N - m * m;
  float r = rsqrtf(var + EPS);
  float g = gamma[c], bt = beta[c];
  uint2 u = *(const uint2*)&y[i];
  float4 v = make_float4(__uint_as_float(u.x << 16), __uint_as_float(u.x & 0xFFFF0000u),
                         __uint_as_float(u.y << 16), __uint_as_float(u.y & 0xFFFF0000u));
  v.x = fmaxf(0.f, (v.x - m) * r * g + bt);
  v.y = fmaxf(0.f, (v.y - m) * r * g + bt);
  v.z = fmaxf(0.f, (v.z - m) * r * g + bt);
  v.w = fmaxf(0.f, (v.w - m) * r * g + bt);
  *(float4*)&out[i] = v;
}

extern "C" void kernel_launch(void* const* d_in, const int* in_sizes, int n_in,
                              void* d_out, int out_size, void* d_ws, size_t ws_size,
                              hipStream_t stream) {
  const float* x     = (const float*)d_in[0];
  const float* w_off = (const float*)d_in[1];
  const float* b_off = (const float*)d_in[2];
  const float* w_dcn = (const float*)d_in[3];
  // d_in[4] = b_dcn: cancels exactly through batch-norm
  const float* gamma = (const float*)d_in[5];
  const float* beta  = (const float*)d_in[6];
  float* out = (float*)d_out;

  float* ws = (float*)d_ws;
  float*  off_buf = ws;                                   // 1,806,336 floats
  float*  psT     = off_buf + 1806336;                    //   802,816 floats
  float*  stats   = psT + 802816;                         //     4,096 (64B-padded)
  ushort* xTb     = (ushort*)(stats + 256 * SSTRIDE);     // 6,422,528 ushorts
  ushort* w_mf    = xTb + (size_t)BATCH * HW * 64;        //    73,728
  ushort* w_offT  = w_mf + COUT * KDIM;                   //    18,432
  ushort* y_bf    = w_offT + 32 * KDIM;                   // 12,845,056 ushorts
  // total ~49 MB

  k_prep<<<dim3(196, 9), 256, 0, stream>>>(x, w_off, w_dcn, xTb, w_offT, w_mf, stats);
  k_offset_conv<<<dim3(HW / 64, BATCH), 256, 0, stream>>>(xTb, w_offT, b_off, off_buf);
  k_deform<<<dim3(HW / TP, BATCH), 256, 0, stream>>>(xTb, off_buf, w_mf, y_bf, psT);
  k_reduce<<<32, 256, 0, stream>>>(psT, stats);
  k_norm<<<BATCH * COUT * HW / 4 / 256, 256, 0, stream>>>(y_bf, stats, gamma, beta, out);
}